// Round 1
// baseline (194.214 us; speedup 1.0000x reference)
//
#include <hip/hip_runtime.h>
#include <hip/hip_bf16.h>

#define B_SZ 8192
#define D_SZ 1024   // elements; == bytes in fp8

typedef __attribute__((ext_vector_type(4))) float floatx4;
typedef __attribute__((ext_vector_type(8))) int   int8v;
typedef __attribute__((ext_vector_type(4))) int   int4v;

__device__ __forceinline__ void glds16(const void* g, void* l) {
    __builtin_amdgcn_global_load_lds(
        (const __attribute__((address_space(1))) void*)g,
        (__attribute__((address_space(3))) void*)l, 16, 0, 0);
}

// One wave per row (rows 0..8191 = img, 8192..16383 = txt). 4 rows/block.
// Also zero-inits the output accumulator (stream-ordered before GEMM atomics).
__global__ __launch_bounds__(256) void norm_cast_fp8(
    const float* __restrict__ img, const float* __restrict__ txt,
    unsigned char* __restrict__ imgQ, unsigned char* __restrict__ txtQ,
    float* __restrict__ out)
{
    if (blockIdx.x == 0 && threadIdx.x == 0) *out = 0.0f;

    const int lane = threadIdx.x & 63;
    int w = blockIdx.x * 4 + (threadIdx.x >> 6);
    const float* src; unsigned char* dst;
    if (w < B_SZ) { src = img + (size_t)w * D_SZ; dst = imgQ + (size_t)w * D_SZ; }
    else { w -= B_SZ; src = txt + (size_t)w * D_SZ; dst = txtQ + (size_t)w * D_SZ; }

    float4 v[4];
    float ss = 0.0f;
    #pragma unroll
    for (int i = 0; i < 4; ++i) {
        v[i] = ((const float4*)src)[lane + 64 * i];
        ss += v[i].x*v[i].x + v[i].y*v[i].y + v[i].z*v[i].z + v[i].w*v[i].w;
    }
    #pragma unroll
    for (int off = 1; off < 64; off <<= 1) ss += __shfl_xor(ss, off, 64);
    const float scale = 1.0f / fmaxf(sqrtf(ss), 1e-12f);

    #pragma unroll
    for (int i = 0; i < 4; ++i) {
        int packed = 0;
        packed = __builtin_amdgcn_cvt_pk_fp8_f32(v[i].x * scale, v[i].y * scale, packed, false);
        packed = __builtin_amdgcn_cvt_pk_fp8_f32(v[i].z * scale, v[i].w * scale, packed, true);
        ((int*)dst)[lane + 64 * i] = packed;
    }
}

// R11: 256x256 block tile, 8 waves (2x4), wave tile 128x64 (8x4 of
// 16x16x128 scaled-MFMA). Deep-pipelined staging in HALF-K-tiles
// (HT = A 256x64B + B 256x64B = 32 KB) across 4 LDS slots (128 KB),
// counted s_waitcnt vmcnt(8) (never 0 in main loop), raw s_barrier
// (no implicit waitcnt drain), setprio around MFMA clusters (T5).
//
// Ledger (per-wave, 4 glds16 per HT, issue order == HT order):
//   prologue: stage HT0..3 (16 loads).
//   iter g (g=0..7) consumes HT pair (2g,2g+1) from slots (2g)&3,(2g+1)&3:
//     vmcnt(8)  -> all but newest 8 loads landed == HTs <= 2g+1 landed.
//     s_barrier -> per-wave guarantee becomes workgroup-wide.
//     reads + 32 MFMA.
//     s_barrier -> all waves done reading slots s0,s1.
//     stage HT 2g+4 -> s0, HT 2g+5 -> s1 (skipped once g>5).
//   last iter: vmcnt(0) (epilogue drain only).
//
// LDS geometry carried over VERBATIM from the validated R9/R10 kernel
// (SQ_LDS_BANK_CONFLICT == 0, absmax == 0): rows x 64-B arrays, staging
// granule g at phys p = g ^ ((row>>1)&3) via GLOBAL-side swizzle;
// fragment reads pos = quad ^ sw retrieve the row-independent
// K-permutation {quad, quad+4}, shared by A and B (MFMA K-order invariant).
__global__ __launch_bounds__(512, 2) void siglip_gemm_loss_fp8(
    const unsigned char* __restrict__ A,   // imgQ [B,D] e4m3
    const unsigned char* __restrict__ Bt,  // txtQ [B,D] e4m3
    const float* __restrict__ tp, const float* __restrict__ bp,
    float* __restrict__ out)
{
    // 4 slots x (A-part 16 KB + B-part 16 KB) = 128 KB (gfx950: 160 KB/CU)
    __shared__ __align__(16) unsigned char lds[4][32768];
    __shared__ float red[8];

    const int tid  = threadIdx.x;
    const int lane = tid & 63;
    const int wave = tid >> 6;     // 0..7
    const int wm = wave >> 2;      // 0..1  (row half)
    const int wn = wave & 3;       // 0..3  (col quarter)
    const int quad = lane >> 4;    // 0..3
    const int l16  = lane & 15;
    const int bi = blockIdx.x * 256;
    const int bj = blockIdx.y * 256;

    floatx4 acc[8][4];
    #pragma unroll
    for (int i = 0; i < 8; ++i)
        #pragma unroll
        for (int j = 0; j < 4; ++j)
            acc[i][j] = (floatx4){0.f, 0.f, 0.f, 0.f};

    // Staging: per array 1024 granule-slots (256 rows x 4); thread handles
    // slots tid and tid+512. slot s -> row = s>>2, phys p = s&3,
    // global granule g = p ^ ((row>>1)&3). LDS dest is LINEAR in lane
    // (wave-uniform base + lane*16 — global_load_lds requirement).
    const int s0i = tid, s1i = tid + 512;
    const int r0 = s0i >> 2, g0 = (s0i & 3) ^ ((r0 >> 1) & 3);
    const int r1 = s1i >> 2, g1 = (s1i & 3) ^ ((r1 >> 1) & 3);
    const unsigned offA0 = (unsigned)(bi + r0) * D_SZ + (unsigned)g0 * 16;
    const unsigned offA1 = (unsigned)(bi + r1) * D_SZ + (unsigned)g1 * 16;
    const unsigned offB0 = (unsigned)(bj + r0) * D_SZ + (unsigned)g0 * 16;
    const unsigned offB1 = (unsigned)(bj + r1) * D_SZ + (unsigned)g1 * 16;

    auto stage = [&](int h, int slot) {   // HT h (K bytes [h*64, h*64+64))
        unsigned char* sb = lds[slot];
        const unsigned ko = (unsigned)h * 64;
        glds16(A  + offA0 + ko, sb + s0i * 16);
        glds16(A  + offA1 + ko, sb + s1i * 16);
        glds16(Bt + offB0 + ko, sb + 16384 + s0i * 16);
        glds16(Bt + offB1 + ko, sb + 16384 + s1i * 16);
    };

    // Prologue: fill all 4 slots (HT0..3 = K bytes [0,256)).
    stage(0, 0); stage(1, 1); stage(2, 2); stage(3, 3);

    // Fragment read addressing (validated swizzle): pos = quad ^ sw.
    const int sw  = (l16 >> 1) & 3;
    const int pos = quad ^ sw;
    const unsigned aoff = (unsigned)((wm * 128 + l16) * 64 + pos * 16);
    const unsigned boff = (unsigned)(16384 + (wn * 64 + l16) * 64 + pos * 16);

    #pragma unroll
    for (int g = 0; g < 8; ++g) {
        const int s0 = (g & 1) * 2, s1 = s0 + 1;

        if (g < 7) asm volatile("s_waitcnt vmcnt(8)" ::: "memory");
        else       asm volatile("s_waitcnt vmcnt(0)" ::: "memory");
        __builtin_amdgcn_sched_barrier(0);
        __builtin_amdgcn_s_barrier();
        __builtin_amdgcn_sched_barrier(0);

        const unsigned char* p0 = lds[s0];   // lo half-K (bytes 128g..+63)
        const unsigned char* p1 = lds[s1];   // hi half-K (bytes 128g+64..+127)

        int8v bfr[4];
        #pragma unroll
        for (int nt = 0; nt < 4; ++nt) {
            int4v lo = *(const int4v*)(p0 + boff + nt * 1024);
            int4v hi = *(const int4v*)(p1 + boff + nt * 1024);
            bfr[nt] = __builtin_shufflevector(lo, hi, 0, 1, 2, 3, 4, 5, 6, 7);
        }

        #pragma unroll
        for (int mt = 0; mt < 8; ++mt) {
            int4v lo = *(const int4v*)(p0 + aoff + mt * 1024);
            int4v hi = *(const int4v*)(p1 + aoff + mt * 1024);
            int8v af = __builtin_shufflevector(lo, hi, 0, 1, 2, 3, 4, 5, 6, 7);
            __builtin_amdgcn_s_setprio(1);
            #pragma unroll
            for (int nt = 0; nt < 4; ++nt)
                acc[mt][nt] = __builtin_amdgcn_mfma_scale_f32_16x16x128_f8f6f4(
                    af, bfr[nt], acc[mt][nt],
                    0, 0,          // cbsz=fp8, blgp=fp8
                    0, 127,        // scale A: E8M0 127 = 1.0
                    0, 127);       // scale B
            __builtin_amdgcn_s_setprio(0);
        }

        if (g < 6) {
            // All waves must be done reading s0/s1 before we restage them.
            __builtin_amdgcn_sched_barrier(0);
            __builtin_amdgcn_s_barrier();
            __builtin_amdgcn_sched_barrier(0);
            stage(2 * g + 4, s0);
            stage(2 * g + 5, s1);
        }
    }

    // Epilogue: softplus(-label*logit) with hw exp/log, reduce.
    const float t    = fminf(__expf(tp[0]), 100.0f);
    const float bias = bp[0];
    float lsum = 0.0f;
    #pragma unroll
    for (int mt = 0; mt < 8; ++mt) {
        #pragma unroll
        for (int nt = 0; nt < 4; ++nt) {
            const int jj = bj + wn * 64 + nt * 16 + l16;                // C/D col
            #pragma unroll
            for (int r = 0; r < 4; ++r) {
                const int ii = bi + wm * 128 + mt * 16 + quad * 4 + r;  // C/D row
                float logit = fmaf(acc[mt][nt][r], t, bias);
                float z = (ii == jj) ? logit : -logit;
                float e = __expf(-fabsf(z));
                lsum += fmaxf(-z, 0.0f) + __logf(1.0f + e);
            }
        }
    }
    #pragma unroll
    for (int off = 32; off > 0; off >>= 1) lsum += __shfl_down(lsum, off, 64);

    if (lane == 0) red[wave] = lsum;
    __syncthreads();
    if (tid == 0) {
        float tot = 0.0f;
        #pragma unroll
        for (int i = 0; i < 8; ++i) tot += red[i];
        atomicAdd(out, tot * (1.0f / (float)B_SZ));
    }
}

extern "C" void kernel_launch(void* const* d_in, const int* in_sizes, int n_in,
                              void* d_out, int out_size, void* d_ws, size_t ws_size,
                              hipStream_t stream) {
    const float* img = (const float*)d_in[0];
    const float* txt = (const float*)d_in[1];
    const float* tp  = (const float*)d_in[2];
    const float* bp  = (const float*)d_in[3];
    float* out = (float*)d_out;

    unsigned char* imgQ = (unsigned char*)d_ws;                   // 8 MB
    unsigned char* txtQ = imgQ + (size_t)B_SZ * D_SZ;             // 8 MB

    norm_cast_fp8<<<(2 * B_SZ) / 4, 256, 0, stream>>>(img, txt, imgQ, txtQ, out);
    dim3 grid(B_SZ / 256, B_SZ / 256);
    siglip_gemm_loss_fp8<<<grid, 512, 0, stream>>>(imgQ, txtQ, tp, bp, out);
}